// Round 1
// baseline (224.095 us; speedup 1.0000x reference)
//
#include <hip/hip_runtime.h>

// MyConv: masked 3x3 conv, B=8, Cin=Cout=128, H=W=128, pad=1, stride=1.
// Implicit GEMM: M=Cout=128, N=B*H*W, K=Cin*9=1152, bf16 MFMA 16x16x32.
// One block per (b, h) row: computes all 128 Cout x 128 w outputs.

typedef __bf16 bf16x8 __attribute__((ext_vector_type(8)));
typedef unsigned short u16x8 __attribute__((ext_vector_type(8)));
typedef float f32x4 __attribute__((ext_vector_type(4)));

#define LDA 40  // padded LDS row stride (ushorts): 40*2B=80B -> bank stride 20, full 32-bank tiling for b128

__device__ __forceinline__ unsigned short f2bf(float f) {
    unsigned int u = __float_as_uint(f);
    u += 0x7fffu + ((u >> 16) & 1u);   // round-to-nearest-even
    return (unsigned short)(u >> 16);
}

__global__ __launch_bounds__(256, 2)
void myconv_kernel(const float* __restrict__ x,
                   const int* __restrict__ mask,
                   const float* __restrict__ wgt,
                   const float* __restrict__ bias,
                   float* __restrict__ out)
{
    __shared__ unsigned short As[128 * LDA];  // A tile: weights [m][k]
    __shared__ unsigned short Bs[128 * LDA];  // B tile: im2col  [n][k]
    __shared__ float act[128];

    const int t   = threadIdx.x;
    const int blk = blockIdx.x;
    const int b   = blk >> 7;    // batch
    const int h   = blk & 127;   // output row

    // ---- active-site map for this (b,h): 3x3 window of mask != 0 ----
    if (t < 128) {
        int any = 0;
        #pragma unroll
        for (int kh = 0; kh < 3; ++kh) {
            int hh = h + kh - 1;
            if ((unsigned)hh < 128u) {
                const int* mrow = mask + (b * 128 + hh) * 128;
                #pragma unroll
                for (int kw = 0; kw < 3; ++kw) {
                    int ww = t + kw - 1;
                    if ((unsigned)ww < 128u) any |= mrow[ww];
                }
            }
        }
        act[t] = any ? 1.0f : 0.0f;
    }

    const int lane = t & 63;
    const int l16  = lane & 15;
    const int half = lane >> 4;
    const int wv   = t >> 6;
    const int wm   = (wv >> 1) << 6;  // wave row offset (0 or 64)
    const int wn   = (wv & 1) << 6;   // wave col offset (0 or 64)

    f32x4 acc[4][4];
    const f32x4 fzero = {0.f, 0.f, 0.f, 0.f};
    #pragma unroll
    for (int i = 0; i < 4; ++i)
        #pragma unroll
        for (int j = 0; j < 4; ++j)
            acc[i][j] = fzero;

    // A staging map: thread -> (m = t>>3 + 32*jj, cols 4*(t&7)..+3)
    const int am  = t >> 3;
    const int ac4 = (t & 7) << 2;
    // B staging map: thread -> column n = t&127, k-half = t>>7 (wave-uniform)
    const int n     = t & 127;
    const int khalf = __builtin_amdgcn_readfirstlane(t >> 7);
    const int xb    = b << 21;  // b * Cin*H*W

    for (int kt = 0; kt < 36; ++kt) {
        __syncthreads();  // previous iter's fragment reads done

        // ---- stage A: weight[m][kt*32 .. +31], fp32 -> bf16 ----
        #pragma unroll
        for (int jj = 0; jj < 4; ++jj) {
            const int m = am + (jj << 5);
            const float4 v = *(const float4*)(wgt + m * 1152 + kt * 32 + ac4);
            unsigned short* dst = &As[m * LDA + ac4];
            dst[0] = f2bf(v.x);
            dst[1] = f2bf(v.y);
            dst[2] = f2bf(v.z);
            dst[3] = f2bf(v.w);
        }

        // ---- stage B: 16 consecutive k for column n (coalesced along n) ----
        u16x8 bv0, bv1;
        #pragma unroll
        for (int s = 0; s < 16; ++s) {
            const int k  = kt * 32 + khalf * 16 + s;  // wave-uniform -> SALU
            const int ci = (k * 7282) >> 16;          // k / 9
            const int r  = k - ci * 9;
            const int kh = (r >= 3) + (r >= 6);
            const int kw = r - kh * 3;
            const int hh = h + kh - 1;                // wave-uniform
            float v = 0.f;
            if ((unsigned)hh < 128u) {                // uniform branch
                const int ww = n + kw - 1;
                if ((unsigned)ww < 128u)              // edge lanes only
                    v = x[xb + (ci << 14) + (hh << 7) + ww];
            }
            if (s < 8) bv0[s] = f2bf(v); else bv1[s - 8] = f2bf(v);
        }
        *(u16x8*)&Bs[n * LDA + khalf * 16]     = bv0;
        *(u16x8*)&Bs[n * LDA + khalf * 16 + 8] = bv1;

        __syncthreads();

        // ---- fragments + MFMA ----
        bf16x8 af[4], bfr[4];
        #pragma unroll
        for (int i = 0; i < 4; ++i)
            af[i] = *(const bf16x8*)&As[(wm + (i << 4) + l16) * LDA + (half << 3)];
        #pragma unroll
        for (int j = 0; j < 4; ++j)
            bfr[j] = *(const bf16x8*)&Bs[(wn + (j << 4) + l16) * LDA + (half << 3)];
        #pragma unroll
        for (int i = 0; i < 4; ++i)
            #pragma unroll
            for (int j = 0; j < 4; ++j)
                acc[i][j] = __builtin_amdgcn_mfma_f32_16x16x32_bf16(af[i], bfr[j], acc[i][j], 0, 0, 0);
    }

    // ---- epilogue: (acc + bias) * active ----
    #pragma unroll
    for (int i = 0; i < 4; ++i) {
        #pragma unroll
        for (int j = 0; j < 4; ++j) {
            const int ncol = wn + (j << 4) + l16;
            const float a  = act[ncol];
            #pragma unroll
            for (int rg = 0; rg < 4; ++rg) {
                const int m = wm + (i << 4) + (half << 2) + rg;
                out[(((b << 7) + m) << 14) + (h << 7) + ncol] =
                    (acc[i][j][rg] + bias[m]) * a;
            }
        }
    }
}

extern "C" void kernel_launch(void* const* d_in, const int* in_sizes, int n_in,
                              void* d_out, int out_size, void* d_ws, size_t ws_size,
                              hipStream_t stream) {
    const float* x    = (const float*)d_in[0];
    const int*   mask = (const int*)d_in[1];
    const float* wgt  = (const float*)d_in[2];
    const float* bias = (const float*)d_in[3];
    float* out        = (float*)d_out;

    myconv_kernel<<<dim3(1024), dim3(256), 0, stream>>>(x, mask, wgt, bias, out);
}

// Round 2
// 165.082 us; speedup vs baseline: 1.3575x; 1.3575x over previous
//
#include <hip/hip_runtime.h>

// MyConv: masked 3x3 conv, B=8, Cin=Cout=128, H=W=128, pad=1, stride=1.
// Implicit GEMM, K reordered as (kh, kw, ci): M=128, N=B*H*W, K=1152.
// Setup kernels pre-convert x->bf16 (layout [b][h][ci][w]) and pre-pack
// weights into per-K-tile bf16 blocks matching the LDS A-tile layout, so the
// main loop stages A via global_load_lds (zero VALU) and B via coalesced
// bf16 loads with immediate offsets.

typedef __bf16 bf16x8 __attribute__((ext_vector_type(8)));
typedef unsigned short u16x8 __attribute__((ext_vector_type(8)));
typedef float f32x4 __attribute__((ext_vector_type(4)));

#define LDB 40  // Bs padded row stride (ushorts)

__device__ __forceinline__ unsigned short f2bf(float f) {
    unsigned int u = __float_as_uint(f);
    u += 0x7fffu + ((u >> 16) & 1u);   // round-to-nearest-even
    return (unsigned short)(u >> 16);
}

// ---- setup: x fp32 [b][ci][h][w] -> bf16 [b][h][ci][w] ----
__global__ void cvt_x(const float* __restrict__ x, unsigned short* __restrict__ xb) {
    const int e  = blockIdx.x * 256 + threadIdx.x;   // 2,097,152 threads
    const int w8 = e & 15;
    const int h  = (e >> 4) & 127;
    const int ci = (e >> 11) & 127;
    const int b  = e >> 18;
    const float* src = x + (((b * 128 + ci) * 128 + h) * 128) + w8 * 8;
    const float4 a = *(const float4*)src;
    const float4 c = *(const float4*)(src + 4);
    u16x8 v;
    v[0] = f2bf(a.x); v[1] = f2bf(a.y); v[2] = f2bf(a.z); v[3] = f2bf(a.w);
    v[4] = f2bf(c.x); v[5] = f2bf(c.y); v[6] = f2bf(c.z); v[7] = f2bf(c.w);
    *(u16x8*)(xb + (((b * 128 + h) * 128 + ci) * 128) + w8 * 8) = v;
}

// ---- setup: pack W into per-K-tile blocks Wp[kt][m][j] (bf16) ----
// kt -> kh=kt/12, kw=(kt/4)%3, cb=kt%4 ; column j is ci = cb*32+j
__global__ void pack_w(const float* __restrict__ wgt, unsigned short* __restrict__ wp) {
    const int e   = blockIdx.x * 256 + threadIdx.x;  // 147,456 threads
    const int kt  = e >> 12;
    const int rem = e & 4095;
    const int m   = rem >> 5;
    const int j   = rem & 31;
    const int kh  = kt / 12;
    const int kw  = (kt >> 2) - kh * 3;
    const int ci  = (kt & 3) * 32 + j;
    wp[e] = f2bf(wgt[((m * 128 + ci) * 3 + kh) * 3 + kw]);
}

__global__ __launch_bounds__(256, 2)
void myconv2(const unsigned short* __restrict__ xb,
             const int* __restrict__ mask,
             const unsigned short* __restrict__ wp,
             const float* __restrict__ bias,
             float* __restrict__ out)
{
    __shared__ unsigned short As[128 * 32];   // A tile [m][k], unpadded (global_load_lds order)
    __shared__ unsigned short Bs[128 * LDB];  // B tile [n][k], padded
    __shared__ float act[128];

    const int t   = threadIdx.x;
    const int blk = blockIdx.x;
    const int b   = blk >> 7;
    const int h   = blk & 127;

    // ---- active map: 3x3 window of mask != 0 ----
    if (t < 128) {
        int any = 0;
        #pragma unroll
        for (int kh = 0; kh < 3; ++kh) {
            int hh = h + kh - 1;
            if ((unsigned)hh < 128u) {
                const int* mrow = mask + (b * 128 + hh) * 128;
                #pragma unroll
                for (int kw = 0; kw < 3; ++kw) {
                    int ww = t + kw - 1;
                    if ((unsigned)ww < 128u) any |= mrow[ww];
                }
            }
        }
        act[t] = any ? 1.0f : 0.0f;
    }

    const int lane  = t & 63;
    const int l16   = lane & 15;
    const int half  = lane >> 4;
    const int wv    = t >> 6;
    const int wm    = (wv >> 1) << 6;
    const int wn    = (wv & 1) << 6;

    f32x4 acc[4][4];
    const f32x4 fzero = {0.f, 0.f, 0.f, 0.f};
    #pragma unroll
    for (int i = 0; i < 4; ++i)
        #pragma unroll
        for (int j = 0; j < 4; ++j)
            acc[i][j] = fzero;

    // B staging map: thread owns column n, ci-half chalf (16 consecutive ci)
    const int n     = t & 127;
    const int chalf = t >> 7;

    // A staging: wave wv copies global bytes [kt*8192 + wv*2048, +2048) -> LDS same offsets
    const unsigned char* agbase = (const unsigned char*)wp + wv * 2048 + lane * 16;

    for (int kt = 0; kt < 36; ++kt) {
        const int kh = kt / 12;
        const int kw = (kt >> 2) - kh * 3;
        const int cb = kt & 3;
        const int hh = h + kh - 1;

        __syncthreads();  // previous iter's fragment reads done

        // ---- stage A via async global->LDS (16B/lane, wave-uniform LDS base) ----
        {
            const unsigned char* g = agbase + kt * 8192;
            __builtin_amdgcn_global_load_lds(
                (const __attribute__((address_space(1))) unsigned int*)g,
                (__attribute__((address_space(3))) unsigned int*)((unsigned char*)As + wv * 2048),
                16, 0, 0);
            __builtin_amdgcn_global_load_lds(
                (const __attribute__((address_space(1))) unsigned int*)(g + 1024),
                (__attribute__((address_space(3))) unsigned int*)((unsigned char*)As + wv * 2048 + 1024),
                16, 0, 0);
        }

        // ---- stage B: 16 ci taps for column n (coalesced, imm offsets) ----
        unsigned short vals[16];
        if ((unsigned)hh < 128u) {            // uniform branch
            const int ww = n + kw - 1;
            if ((unsigned)ww < 128u) {        // 2 edge lanes only
                const unsigned short* src =
                    xb + (((b * 128 + hh) * 128 + cb * 32 + chalf * 16) * 128) + ww;
                #pragma unroll
                for (int s = 0; s < 16; ++s) vals[s] = src[s * 128];
            } else {
                #pragma unroll
                for (int s = 0; s < 16; ++s) vals[s] = 0;
            }
        } else {
            #pragma unroll
            for (int s = 0; s < 16; ++s) vals[s] = 0;
        }
        *(u16x8*)&Bs[n * LDB + chalf * 16]     = *(u16x8*)&vals[0];
        *(u16x8*)&Bs[n * LDB + chalf * 16 + 8] = *(u16x8*)&vals[8];

        __syncthreads();

        // ---- fragments + MFMA ----
        bf16x8 af[4], bfr[4];
        #pragma unroll
        for (int i = 0; i < 4; ++i)
            af[i] = *(const bf16x8*)&As[(wm + (i << 4) + l16) * 32 + (half << 3)];
        #pragma unroll
        for (int j = 0; j < 4; ++j)
            bfr[j] = *(const bf16x8*)&Bs[(wn + (j << 4) + l16) * LDB + (half << 3)];
        #pragma unroll
        for (int i = 0; i < 4; ++i)
            #pragma unroll
            for (int j = 0; j < 4; ++j)
                acc[i][j] = __builtin_amdgcn_mfma_f32_16x16x32_bf16(af[i], bfr[j], acc[i][j], 0, 0, 0);
    }

    // ---- epilogue: (acc + bias) * active ----
    #pragma unroll
    for (int i = 0; i < 4; ++i) {
        #pragma unroll
        for (int j = 0; j < 4; ++j) {
            const int ncol = wn + (j << 4) + l16;
            const float a  = act[ncol];
            #pragma unroll
            for (int rg = 0; rg < 4; ++rg) {
                const int m = wm + (i << 4) + (half << 2) + rg;
                out[(((b << 7) + m) << 14) + (h << 7) + ncol] =
                    (acc[i][j][rg] + bias[m]) * a;
            }
        }
    }
}

// ---------------- Round-1 fallback (used only if ws too small) ----------------
#define LDAF 40
__global__ __launch_bounds__(256, 2)
void myconv_fb(const float* __restrict__ x,
               const int* __restrict__ mask,
               const float* __restrict__ wgt,
               const float* __restrict__ bias,
               float* __restrict__ out)
{
    __shared__ unsigned short As[128 * LDAF];
    __shared__ unsigned short Bs[128 * LDAF];
    __shared__ float act[128];

    const int t   = threadIdx.x;
    const int blk = blockIdx.x;
    const int b   = blk >> 7;
    const int h   = blk & 127;

    if (t < 128) {
        int any = 0;
        #pragma unroll
        for (int kh = 0; kh < 3; ++kh) {
            int hh = h + kh - 1;
            if ((unsigned)hh < 128u) {
                const int* mrow = mask + (b * 128 + hh) * 128;
                #pragma unroll
                for (int kw = 0; kw < 3; ++kw) {
                    int ww = t + kw - 1;
                    if ((unsigned)ww < 128u) any |= mrow[ww];
                }
            }
        }
        act[t] = any ? 1.0f : 0.0f;
    }

    const int lane = t & 63;
    const int l16  = lane & 15;
    const int half = lane >> 4;
    const int wv   = t >> 6;
    const int wm   = (wv >> 1) << 6;
    const int wn   = (wv & 1) << 6;

    f32x4 acc[4][4];
    const f32x4 fzero = {0.f, 0.f, 0.f, 0.f};
    #pragma unroll
    for (int i = 0; i < 4; ++i)
        #pragma unroll
        for (int j = 0; j < 4; ++j)
            acc[i][j] = fzero;

    const int am  = t >> 3;
    const int ac4 = (t & 7) << 2;
    const int n     = t & 127;
    const int khalf = __builtin_amdgcn_readfirstlane(t >> 7);
    const int xb    = b << 21;

    for (int kt = 0; kt < 36; ++kt) {
        __syncthreads();
        #pragma unroll
        for (int jj = 0; jj < 4; ++jj) {
            const int m = am + (jj << 5);
            const float4 v = *(const float4*)(wgt + m * 1152 + kt * 32 + ac4);
            unsigned short* dst = &As[m * LDAF + ac4];
            dst[0] = f2bf(v.x); dst[1] = f2bf(v.y); dst[2] = f2bf(v.z); dst[3] = f2bf(v.w);
        }
        u16x8 bv0, bv1;
        #pragma unroll
        for (int s = 0; s < 16; ++s) {
            const int k  = kt * 32 + khalf * 16 + s;
            const int ci = (k * 7282) >> 16;
            const int r  = k - ci * 9;
            const int kh = (r >= 3) + (r >= 6);
            const int kw = r - kh * 3;
            const int hh = h + kh - 1;
            float v = 0.f;
            if ((unsigned)hh < 128u) {
                const int ww = n + kw - 1;
                if ((unsigned)ww < 128u)
                    v = x[xb + (ci << 14) + (hh << 7) + ww];
            }
            if (s < 8) bv0[s] = f2bf(v); else bv1[s - 8] = f2bf(v);
        }
        *(u16x8*)&Bs[n * LDAF + khalf * 16]     = bv0;
        *(u16x8*)&Bs[n * LDAF + khalf * 16 + 8] = bv1;

        __syncthreads();

        bf16x8 af[4], bfr[4];
        #pragma unroll
        for (int i = 0; i < 4; ++i)
            af[i] = *(const bf16x8*)&As[(wm + (i << 4) + l16) * LDAF + (half << 3)];
        #pragma unroll
        for (int j = 0; j < 4; ++j)
            bfr[j] = *(const bf16x8*)&Bs[(wn + (j << 4) + l16) * LDAF + (half << 3)];
        #pragma unroll
        for (int i = 0; i < 4; ++i)
            #pragma unroll
            for (int j = 0; j < 4; ++j)
                acc[i][j] = __builtin_amdgcn_mfma_f32_16x16x32_bf16(af[i], bfr[j], acc[i][j], 0, 0, 0);
    }

    #pragma unroll
    for (int i = 0; i < 4; ++i) {
        #pragma unroll
        for (int j = 0; j < 4; ++j) {
            const int ncol = wn + (j << 4) + l16;
            const float a  = act[ncol];
            #pragma unroll
            for (int rg = 0; rg < 4; ++rg) {
                const int m = wm + (i << 4) + (half << 2) + rg;
                out[(((b << 7) + m) << 14) + (h << 7) + ncol] =
                    (acc[i][j][rg] + bias[m]) * a;
            }
        }
    }
}

extern "C" void kernel_launch(void* const* d_in, const int* in_sizes, int n_in,
                              void* d_out, int out_size, void* d_ws, size_t ws_size,
                              hipStream_t stream) {
    const float* x    = (const float*)d_in[0];
    const int*   mask = (const int*)d_in[1];
    const float* wgt  = (const float*)d_in[2];
    const float* bias = (const float*)d_in[3];
    float* out        = (float*)d_out;

    const size_t XB_ELEMS = 8ull * 128 * 128 * 128;        // 16,777,216 bf16
    const size_t WP_ELEMS = 36ull * 128 * 32;              // 147,456 bf16
    const size_t need = (XB_ELEMS + WP_ELEMS) * 2;

    if (ws_size >= need) {
        unsigned short* xb = (unsigned short*)d_ws;
        unsigned short* wp = xb + XB_ELEMS;
        cvt_x<<<dim3(8192), dim3(256), 0, stream>>>(x, xb);
        pack_w<<<dim3(576), dim3(256), 0, stream>>>(wgt, wp);
        myconv2<<<dim3(1024), dim3(256), 0, stream>>>(xb, mask, wp, bias, out);
    } else {
        myconv_fb<<<dim3(1024), dim3(256), 0, stream>>>(x, mask, wgt, bias, out);
    }
}

// Round 3
// 157.819 us; speedup vs baseline: 1.4199x; 1.0460x over previous
//
#include <hip/hip_runtime.h>

// MyConv: masked 3x3 conv, B=8, Cin=Cout=128, H=W=128, pad=1, stride=1.
// Implicit GEMM over K=(kh,cb,ci32) rounds. x is pre-converted to bf16 in a
// guarded layout xp[b][hh2=130][cb=4][w'=130][ci=32] (rows hh2=0/129 and
// w'=0/129 are zeros), so each (kh,cb) round's B tile is ONE contiguous 8320B
// block staged via global_load_lds; the 3 kw taps are row offsets in LDS.
// Weights pre-packed wp[kh][cb][kw][m][ci32] so each round's 3 A tiles are a
// contiguous 24KB global_load_lds copy. 48 MFMA per barrier pair, 12 rounds.

typedef __bf16 bf16x8 __attribute__((ext_vector_type(8)));
typedef unsigned short u16x8 __attribute__((ext_vector_type(8)));
typedef float f32x4 __attribute__((ext_vector_type(4)));

__device__ __forceinline__ unsigned short f2bf(float f) {
    unsigned int u = __float_as_uint(f);
    u += 0x7fffu + ((u >> 16) & 1u);   // round-to-nearest-even
    return (unsigned short)(u >> 16);
}

// ---- setup: x fp32 [b][ci][h][w] -> bf16 xp[b][130][4][130][32] with guards ----
__global__ void cvt_x2(const float* __restrict__ x, unsigned short* __restrict__ xp) {
    const int t   = threadIdx.x;
    const int b   = blockIdx.x / 130;
    const int hh2 = blockIdx.x % 130;
    unsigned short* dst = xp + (size_t)((b * 130 + hh2) * 4) * 4160;
    const u16x8 z = {0, 0, 0, 0, 0, 0, 0, 0};
    if (hh2 == 0 || hh2 == 129) {
        // zero the whole 4-slab group: 4*4160 = 16640 u16 = 2080 x (8 u16)
        for (int i = t; i < 2080; i += 256) ((u16x8*)dst)[i] = z;
        return;
    }
    const int h  = hh2 - 1;
    const int hf = t >> 7;     // ci 16-half
    const int w  = t & 127;
    #pragma unroll
    for (int cb = 0; cb < 4; ++cb) {
        unsigned short* slab = dst + cb * 4160;
        if (t < 2) {  // guard rows w' = 0 and 129
            unsigned short* gr = slab + (t == 0 ? 0 : 129) * 32;
            ((u16x8*)gr)[0] = z; ((u16x8*)gr)[1] = z;
            ((u16x8*)gr)[2] = z; ((u16x8*)gr)[3] = z;
        }
        u16x8 v0, v1;
        #pragma unroll
        for (int s = 0; s < 8; ++s)
            v0[s] = f2bf(x[((b * 128 + cb * 32 + hf * 16 + s) * 128 + h) * 128 + w]);
        #pragma unroll
        for (int s = 0; s < 8; ++s)
            v1[s] = f2bf(x[((b * 128 + cb * 32 + hf * 16 + 8 + s) * 128 + h) * 128 + w]);
        *(u16x8*)(slab + (1 + w) * 32 + hf * 16)     = v0;
        *(u16x8*)(slab + (1 + w) * 32 + hf * 16 + 8) = v1;
    }
}

// ---- setup: pack W -> wp[kh][cb][kw][m][ci32] bf16 ----
__global__ void pack_w2(const float* __restrict__ wgt, unsigned short* __restrict__ wp) {
    const int e    = blockIdx.x * 256 + threadIdx.x;  // 147,456 threads
    const int j    = e & 31;
    const int m    = (e >> 5) & 127;
    const int r    = e >> 12;        // 0..35 = (kh*4+cb)*3 + kw
    const int kw   = r - (r / 3) * 3;
    const int cbkh = r / 3;
    const int cb   = cbkh & 3;
    const int kh   = cbkh >> 2;
    const int ci   = cb * 32 + j;
    wp[e] = f2bf(wgt[((m * 128 + ci) * 3 + kh) * 3 + kw]);
}

__global__ __launch_bounds__(256, 4)
void myconv3(const unsigned short* __restrict__ xp,
             const int* __restrict__ mask,
             const unsigned short* __restrict__ wp,
             const float* __restrict__ bias,
             float* __restrict__ out)
{
    __shared__ unsigned short As[3 * 128 * 32];  // [kw][m][ci32], 24576 B
    __shared__ unsigned short Xs[130 * 32];      // [w'][ci32],     8320 B
    __shared__ float act[128];

    const int t   = threadIdx.x;
    const int blk = blockIdx.x;
    const int b   = blk >> 7;
    const int h   = blk & 127;

    // ---- active map: 3x3 window of mask != 0 ----
    if (t < 128) {
        int any = 0;
        #pragma unroll
        for (int kh = 0; kh < 3; ++kh) {
            int hh = h + kh - 1;
            if ((unsigned)hh < 128u) {
                const int* mrow = mask + (b * 128 + hh) * 128;
                #pragma unroll
                for (int kw = 0; kw < 3; ++kw) {
                    int ww = t + kw - 1;
                    if ((unsigned)ww < 128u) any |= mrow[ww];
                }
            }
        }
        act[t] = any ? 1.0f : 0.0f;
    }

    const int lane = t & 63;
    const int l16  = lane & 15;
    const int q    = lane >> 4;      // 0..3, k-chunk
    const int wv   = t >> 6;
    const int wm   = (wv >> 1) << 6;
    const int wn   = (wv & 1) << 6;

    f32x4 acc[4][4];
    const f32x4 fzero = {0.f, 0.f, 0.f, 0.f};
    #pragma unroll
    for (int i = 0; i < 4; ++i)
        #pragma unroll
        for (int j = 0; j < 4; ++j)
            acc[i][j] = fzero;

    const unsigned char* wpB = (const unsigned char*)wp;
    const unsigned char* xpB = (const unsigned char*)xp;

    for (int kh = 0; kh < 3; ++kh) {
        for (int cb = 0; cb < 4; ++cb) {
            __syncthreads();  // previous round's fragment reads done

            // ---- stage A: 24576B contiguous, 6 x 1KB per wave ----
            {
                const unsigned char* ga =
                    wpB + (kh * 4 + cb) * 24576 + wv * 6144 + lane * 16;
                #pragma unroll
                for (int u = 0; u < 6; ++u)
                    __builtin_amdgcn_global_load_lds(
                        (const __attribute__((address_space(1))) unsigned int*)(ga + u * 1024),
                        (__attribute__((address_space(3))) unsigned int*)((unsigned char*)As + wv * 6144 + u * 1024),
                        16, 0, 0);
            }
            // ---- stage B: 8320B contiguous (guards included, no branches) ----
            {
                const unsigned char* gx =
                    xpB + (size_t)(((b * 130 + h + kh) * 4 + cb)) * 8320;
                #pragma unroll
                for (int u = 0; u < 2; ++u)
                    __builtin_amdgcn_global_load_lds(
                        (const __attribute__((address_space(1))) unsigned int*)(gx + wv * 2048 + u * 1024 + lane * 16),
                        (__attribute__((address_space(3))) unsigned int*)((unsigned char*)Xs + wv * 2048 + u * 1024),
                        16, 0, 0);
                if (t < 8)   // 128B tail (rows 128,129)
                    __builtin_amdgcn_global_load_lds(
                        (const __attribute__((address_space(1))) unsigned int*)(gx + 8192 + t * 16),
                        (__attribute__((address_space(3))) unsigned int*)((unsigned char*)Xs + 8192),
                        16, 0, 0);
            }

            __syncthreads();

            // ---- 3 kw taps: row-shifted fragment reads, 48 MFMA ----
            #pragma unroll
            for (int kw = 0; kw < 3; ++kw) {
                bf16x8 af[4], bfr[4];
                #pragma unroll
                for (int i = 0; i < 4; ++i)
                    af[i] = *(const bf16x8*)&As[kw * 4096 + (wm + (i << 4) + l16) * 32 + (q << 3)];
                #pragma unroll
                for (int j = 0; j < 4; ++j)
                    bfr[j] = *(const bf16x8*)&Xs[(wn + (j << 4) + l16 + kw) * 32 + (q << 3)];
                #pragma unroll
                for (int i = 0; i < 4; ++i)
                    #pragma unroll
                    for (int j = 0; j < 4; ++j)
                        acc[i][j] = __builtin_amdgcn_mfma_f32_16x16x32_bf16(af[i], bfr[j], acc[i][j], 0, 0, 0);
            }
        }
    }

    // ---- epilogue: (acc + bias) * active ----
    #pragma unroll
    for (int i = 0; i < 4; ++i) {
        #pragma unroll
        for (int j = 0; j < 4; ++j) {
            const int ncol = wn + (j << 4) + l16;
            const float a  = act[ncol];
            #pragma unroll
            for (int rg = 0; rg < 4; ++rg) {
                const int m = wm + (i << 4) + (q << 2) + rg;
                out[(((b << 7) + m) << 14) + (h << 7) + ncol] =
                    (acc[i][j][rg] + bias[m]) * a;
            }
        }
    }
}

// ---------------- Round-1 fallback (used only if ws too small) ----------------
#define LDAF 40
__global__ __launch_bounds__(256, 2)
void myconv_fb(const float* __restrict__ x,
               const int* __restrict__ mask,
               const float* __restrict__ wgt,
               const float* __restrict__ bias,
               float* __restrict__ out)
{
    __shared__ unsigned short As[128 * LDAF];
    __shared__ unsigned short Bs[128 * LDAF];
    __shared__ float act[128];

    const int t   = threadIdx.x;
    const int blk = blockIdx.x;
    const int b   = blk >> 7;
    const int h   = blk & 127;

    if (t < 128) {
        int any = 0;
        #pragma unroll
        for (int kh = 0; kh < 3; ++kh) {
            int hh = h + kh - 1;
            if ((unsigned)hh < 128u) {
                const int* mrow = mask + (b * 128 + hh) * 128;
                #pragma unroll
                for (int kw = 0; kw < 3; ++kw) {
                    int ww = t + kw - 1;
                    if ((unsigned)ww < 128u) any |= mrow[ww];
                }
            }
        }
        act[t] = any ? 1.0f : 0.0f;
    }

    const int lane = t & 63;
    const int l16  = lane & 15;
    const int half = lane >> 4;
    const int wv   = t >> 6;
    const int wm   = (wv >> 1) << 6;
    const int wn   = (wv & 1) << 6;

    f32x4 acc[4][4];
    const f32x4 fzero = {0.f, 0.f, 0.f, 0.f};
    #pragma unroll
    for (int i = 0; i < 4; ++i)
        #pragma unroll
        for (int j = 0; j < 4; ++j)
            acc[i][j] = fzero;

    const int am  = t >> 3;
    const int ac4 = (t & 7) << 2;
    const int n     = t & 127;
    const int khalf = __builtin_amdgcn_readfirstlane(t >> 7);
    const int xb    = b << 21;

    for (int kt = 0; kt < 36; ++kt) {
        __syncthreads();
        #pragma unroll
        for (int jj = 0; jj < 4; ++jj) {
            const int m = am + (jj << 5);
            const float4 v = *(const float4*)(wgt + m * 1152 + kt * 32 + ac4);
            unsigned short* dst = &As[m * LDAF + ac4];
            dst[0] = f2bf(v.x); dst[1] = f2bf(v.y); dst[2] = f2bf(v.z); dst[3] = f2bf(v.w);
        }
        u16x8 bv0, bv1;
        #pragma unroll
        for (int s = 0; s < 16; ++s) {
            const int k  = kt * 32 + khalf * 16 + s;
            const int ci = (k * 7282) >> 16;
            const int r  = k - ci * 9;
            const int kh = (r >= 3) + (r >= 6);
            const int kw = r - kh * 3;
            const int hh = h + kh - 1;
            float v = 0.f;
            if ((unsigned)hh < 128u) {
                const int ww = n + kw - 1;
                if ((unsigned)ww < 128u)
                    v = x[xb + (ci << 14) + (hh << 7) + ww];
            }
            if (s < 8) bv0[s] = f2bf(v); else bv1[s - 8] = f2bf(v);
        }
        *(u16x8*)&Bs[n * LDAF + khalf * 16]     = bv0;
        *(u16x8*)&Bs[n * LDAF + khalf * 16 + 8] = bv1;

        __syncthreads();

        bf16x8 af[4], bfr[4];
        #pragma unroll
        for (int i = 0; i < 4; ++i)
            af[i] = *(const bf16x8*)&As[(wm + (i << 4) + l16) * LDAF + (half << 3)];
        #pragma unroll
        for (int j = 0; j < 4; ++j)
            bfr[j] = *(const bf16x8*)&Bs[(wn + (j << 4) + l16) * LDAF + (half << 3)];
        #pragma unroll
        for (int i = 0; i < 4; ++i)
            #pragma unroll
            for (int j = 0; j < 4; ++j)
                acc[i][j] = __builtin_amdgcn_mfma_f32_16x16x32_bf16(af[i], bfr[j], acc[i][j], 0, 0, 0);
    }

    #pragma unroll
    for (int i = 0; i < 4; ++i) {
        #pragma unroll
        for (int j = 0; j < 4; ++j) {
            const int ncol = wn + (j << 4) + l16;
            const float a  = act[ncol];
            #pragma unroll
            for (int rg = 0; rg < 4; ++rg) {
                const int m = wm + (i << 4) + (half << 2) + rg;
                out[(((b << 7) + m) << 14) + (h << 7) + ncol] =
                    (acc[i][j][rg] + bias[m]) * a;
            }
        }
    }
}

extern "C" void kernel_launch(void* const* d_in, const int* in_sizes, int n_in,
                              void* d_out, int out_size, void* d_ws, size_t ws_size,
                              hipStream_t stream) {
    const float* x    = (const float*)d_in[0];
    const int*   mask = (const int*)d_in[1];
    const float* wgt  = (const float*)d_in[2];
    const float* bias = (const float*)d_in[3];
    float* out        = (float*)d_out;

    const size_t XP_ELEMS = 8ull * 130 * 4 * 130 * 32;  // 17,305,600 bf16
    const size_t WP_ELEMS = 36ull * 128 * 32;           //    147,456 bf16
    const size_t need = (XP_ELEMS + WP_ELEMS) * 2;

    if (ws_size >= need) {
        unsigned short* xpw = (unsigned short*)d_ws;
        unsigned short* wpw = xpw + XP_ELEMS;
        cvt_x2<<<dim3(1040), dim3(256), 0, stream>>>(x, xpw);
        pack_w2<<<dim3(576), dim3(256), 0, stream>>>(wgt, wpw);
        myconv3<<<dim3(1024), dim3(256), 0, stream>>>(xpw, mask, wpw, bias, out);
    } else {
        myconv_fb<<<dim3(1024), dim3(256), 0, stream>>>(x, mask, wgt, bias, out);
    }
}

// Round 4
// 155.308 us; speedup vs baseline: 1.4429x; 1.0162x over previous
//
#include <hip/hip_runtime.h>

// MyConv: masked 3x3 conv, B=8, Cin=Cout=128, H=W=128, pad=1, stride=1.
// Implicit GEMM over rounds (kh,cb). v4:
//  - xp[b][cb][hh2=130][w'=130][ci32] bf16, guard rows zero, 16B chunks
//    XOR-swizzled: chunk c of row w' stored at slot c^(w'&3)  (kills LDS
//    bank conflicts after global_load_lds, which forbids padding).
//  - Block = 128 Cout x 256 (two h rows). 4 waves, wave tile 64x128,
//    acc 4x8. B tile (2 slabs, 16640B contiguous) staged via
//    global_load_lds; A fragments loaded DIRECTLY from global (wp is
//    contiguous per-fragment, L2-resident) so LDS carries only B.
//  - 96 MFMA per barrier pair, 12 rounds.

typedef __bf16 bf16x8 __attribute__((ext_vector_type(8)));
typedef unsigned short u16x8 __attribute__((ext_vector_type(8)));
typedef float f32x4 __attribute__((ext_vector_type(4)));

__device__ __forceinline__ unsigned short f2bf(float f) {
    unsigned int u = __float_as_uint(f);
    u += 0x7fffu + ((u >> 16) & 1u);   // round-to-nearest-even
    return (unsigned short)(u >> 16);
}

// ---- setup: x fp32 [b][ci][h][w] -> bf16 xp[b][cb][hh2][w'][ci32], swizzled ----
// slab = (b*4+cb)*130 + hh2 ; 520 chunks of 16B per slab (8320B).
// chunk k: r=k>>2 (w' row), slot c=k&3 holds ci-group (c ^ (r&3)).
__global__ void cvt_x3(const float* __restrict__ x, unsigned short* __restrict__ xp) {
    __shared__ float Lf[32 * 132];   // [ci][w], stride 132 (16B-aligned rows)
    const int t   = threadIdx.x;
    const int hh2 = blockIdx.x % 130;
    const int cb  = (blockIdx.x / 130) & 3;
    const int b   = blockIdx.x / 520;
    u16x8* slab = (u16x8*)(xp + (size_t)(((b * 4 + cb) * 130 + hh2)) * 4160);
    const u16x8 z = {0, 0, 0, 0, 0, 0, 0, 0};

    if (hh2 == 0 || hh2 == 129) {    // guard slab: all zeros
        for (int k = t; k < 520; k += 256) slab[k] = z;
        return;
    }
    const int h = hh2 - 1;

    #pragma unroll
    for (int u = 0; u < 4; ++u) {
        const int f  = t + 256 * u;       // 0..1023
        const int ci = f >> 5;
        const int w4 = f & 31;
        const float4 v = *(const float4*)(x + (((b * 128 + cb * 32 + ci) * 128 + h) << 7) + (w4 << 2));
        *(float4*)&Lf[ci * 132 + (w4 << 2)] = v;
    }
    __syncthreads();

    for (int k = t; k < 520; k += 256) {
        const int r = k >> 2;
        const int c = k & 3;
        u16x8 o;
        if (r == 0 || r == 129) {
            o = z;
        } else {
            const int w   = r - 1;
            const int ci0 = (c ^ (r & 3)) << 3;
            #pragma unroll
            for (int s = 0; s < 8; ++s) o[s] = f2bf(Lf[(ci0 + s) * 132 + w]);
        }
        slab[k] = o;
    }
}

// ---- setup: pack W -> wp[kh][cb][kw][m][ci32] bf16 (no swizzle; read direct) ----
__global__ void pack_w2(const float* __restrict__ wgt, unsigned short* __restrict__ wp) {
    const int e    = blockIdx.x * 256 + threadIdx.x;  // 147,456 threads
    const int j    = e & 31;
    const int m    = (e >> 5) & 127;
    const int r    = e >> 12;        // (kh*4+cb)*3 + kw
    const int kw   = r - (r / 3) * 3;
    const int cbkh = r / 3;
    const int cb   = cbkh & 3;
    const int kh   = cbkh >> 2;
    const int ci   = cb * 32 + j;
    wp[e] = f2bf(wgt[((m * 128 + ci) * 3 + kh) * 3 + kw]);
}

__global__ __launch_bounds__(256, 2)
void myconv4(const unsigned short* __restrict__ xp,
             const int* __restrict__ mask,
             const unsigned short* __restrict__ wp,
             const float* __restrict__ bias,
             float* __restrict__ out)
{
    __shared__ unsigned char Xs[16640];  // two slabs [g][w'][ci32], swizzled, contiguous
    __shared__ float act[256];           // [g][w]

    const int t  = threadIdx.x;
    const int b  = blockIdx.x >> 6;
    const int h0 = (blockIdx.x & 63) << 1;

    // ---- active map for rows h0, h0+1 ----
    {
        const int g = t >> 7;
        const int w = t & 127;
        const int h = h0 + g;
        int any = 0;
        #pragma unroll
        for (int kh = 0; kh < 3; ++kh) {
            int hh = h + kh - 1;
            if ((unsigned)hh < 128u) {
                const int* mrow = mask + (b * 128 + hh) * 128;
                #pragma unroll
                for (int kw = 0; kw < 3; ++kw) {
                    int ww = w + kw - 1;
                    if ((unsigned)ww < 128u) any |= mrow[ww];
                }
            }
        }
        act[t] = any ? 1.0f : 0.0f;
    }

    const int lane = t & 63;
    const int l16  = lane & 15;
    const int q    = lane >> 4;
    const int wv   = t >> 6;
    const int wm   = (wv & 1) << 6;   // Cout offset
    const int g    = wv >> 1;         // which h row

    f32x4 acc[4][8];
    const f32x4 fzero = {0.f, 0.f, 0.f, 0.f};
    #pragma unroll
    for (int i = 0; i < 4; ++i)
        #pragma unroll
        for (int j = 0; j < 8; ++j)
            acc[i][j] = fzero;

    // B fragment base byte-offsets into Xs, one per kw (constant across rounds):
    // row w' = j*16 + l16 + kw, slot = q ^ ((l16+kw)&3); + j*1024 at read time.
    int bb[3];
    #pragma unroll
    for (int kw = 0; kw < 3; ++kw)
        bb[kw] = g * 8320 + (l16 + kw) * 64 + ((q ^ ((l16 + kw) & 3)) << 4);

    const unsigned char* agl = (const unsigned char*)wp + (wm + l16) * 64 + q * 16;
    const unsigned char* xpB = (const unsigned char*)xp;

    for (int kh = 0; kh < 3; ++kh) {
        for (int cb = 0; cb < 4; ++cb) {
            __syncthreads();  // previous round's Xs reads done

            // ---- stage B: 2 slabs, 16640B contiguous ----
            const unsigned char* gx =
                xpB + (size_t)((b * 4 + cb) * 130 + h0 + kh) * 8320;
            #pragma unroll
            for (int u = 0; u < 4; ++u)
                __builtin_amdgcn_global_load_lds(
                    (const __attribute__((address_space(1))) unsigned int*)(gx + ((wv << 2) + u) * 1024 + lane * 16),
                    (__attribute__((address_space(3))) unsigned int*)(Xs + ((wv << 2) + u) * 1024),
                    16, 0, 0);
            if (t < 16)   // 256B tail (lanes 0-15 of wave 0)
                __builtin_amdgcn_global_load_lds(
                    (const __attribute__((address_space(1))) unsigned int*)(gx + 16384 + t * 16),
                    (__attribute__((address_space(3))) unsigned int*)(Xs + 16384),
                    16, 0, 0);

            __syncthreads();

            const unsigned char* ar = agl + (kh * 4 + cb) * 24576;
            #pragma unroll
            for (int kw = 0; kw < 3; ++kw) {
                bf16x8 af[4];
                #pragma unroll
                for (int i = 0; i < 4; ++i)
                    af[i] = *(const bf16x8*)(ar + kw * 8192 + i * 1024);
                bf16x8 bfr[8];
                #pragma unroll
                for (int j = 0; j < 8; ++j)
                    bfr[j] = *(const bf16x8*)(Xs + bb[kw] + j * 1024);
                #pragma unroll
                for (int i = 0; i < 4; ++i)
                    #pragma unroll
                    for (int j = 0; j < 8; ++j)
                        acc[i][j] = __builtin_amdgcn_mfma_f32_16x16x32_bf16(af[i], bfr[j], acc[i][j], 0, 0, 0);
            }
        }
    }

    // ---- epilogue: (acc + bias) * active ----
    #pragma unroll
    for (int i = 0; i < 4; ++i) {
        const f32x4 bv = *(const f32x4*)(bias + wm + (i << 4) + (q << 2));
        #pragma unroll
        for (int j = 0; j < 8; ++j) {
            const int w = (j << 4) + l16;
            const float a = act[(g << 7) + w];
            float* base = out + (((((b << 7) + wm + (i << 4) + (q << 2)) << 7) + h0 + g) << 7) + w;
            #pragma unroll
            for (int rg = 0; rg < 4; ++rg)
                base[rg << 14] = (acc[i][j][rg] + bv[rg]) * a;
        }
    }
}

// ---------------- Round-1 fallback (used only if ws too small) ----------------
#define LDAF 40
__global__ __launch_bounds__(256, 2)
void myconv_fb(const float* __restrict__ x,
               const int* __restrict__ mask,
               const float* __restrict__ wgt,
               const float* __restrict__ bias,
               float* __restrict__ out)
{
    __shared__ unsigned short As[128 * LDAF];
    __shared__ unsigned short Bs[128 * LDAF];
    __shared__ float act[128];

    const int t   = threadIdx.x;
    const int blk = blockIdx.x;
    const int b   = blk >> 7;
    const int h   = blk & 127;

    if (t < 128) {
        int any = 0;
        #pragma unroll
        for (int kh = 0; kh < 3; ++kh) {
            int hh = h + kh - 1;
            if ((unsigned)hh < 128u) {
                const int* mrow = mask + (b * 128 + hh) * 128;
                #pragma unroll
                for (int kw = 0; kw < 3; ++kw) {
                    int ww = t + kw - 1;
                    if ((unsigned)ww < 128u) any |= mrow[ww];
                }
            }
        }
        act[t] = any ? 1.0f : 0.0f;
    }

    const int lane = t & 63;
    const int l16  = lane & 15;
    const int half = lane >> 4;
    const int wv   = t >> 6;
    const int wm   = (wv >> 1) << 6;
    const int wn   = (wv & 1) << 6;

    f32x4 acc[4][4];
    const f32x4 fzero = {0.f, 0.f, 0.f, 0.f};
    #pragma unroll
    for (int i = 0; i < 4; ++i)
        #pragma unroll
        for (int j = 0; j < 4; ++j)
            acc[i][j] = fzero;

    const int am  = t >> 3;
    const int ac4 = (t & 7) << 2;
    const int n     = t & 127;
    const int khalf = __builtin_amdgcn_readfirstlane(t >> 7);
    const int xb    = b << 21;

    for (int kt = 0; kt < 36; ++kt) {
        __syncthreads();
        #pragma unroll
        for (int jj = 0; jj < 4; ++jj) {
            const int m = am + (jj << 5);
            const float4 v = *(const float4*)(wgt + m * 1152 + kt * 32 + ac4);
            unsigned short* dst = &As[m * LDAF + ac4];
            dst[0] = f2bf(v.x); dst[1] = f2bf(v.y); dst[2] = f2bf(v.z); dst[3] = f2bf(v.w);
        }
        u16x8 bv0, bv1;
        #pragma unroll
        for (int s = 0; s < 16; ++s) {
            const int k  = kt * 32 + khalf * 16 + s;
            const int ci = (k * 7282) >> 16;
            const int r  = k - ci * 9;
            const int kh = (r >= 3) + (r >= 6);
            const int kw = r - kh * 3;
            const int hh = h + kh - 1;
            float v = 0.f;
            if ((unsigned)hh < 128u) {
                const int ww = n + kw - 1;
                if ((unsigned)ww < 128u)
                    v = x[xb + (ci << 14) + (hh << 7) + ww];
            }
            if (s < 8) bv0[s] = f2bf(v); else bv1[s - 8] = f2bf(v);
        }
        *(u16x8*)&Bs[n * LDAF + khalf * 16]     = bv0;
        *(u16x8*)&Bs[n * LDAF + khalf * 16 + 8] = bv1;

        __syncthreads();

        bf16x8 af[4], bfr[4];
        #pragma unroll
        for (int i = 0; i < 4; ++i)
            af[i] = *(const bf16x8*)&As[(wm + (i << 4) + l16) * LDAF + (half << 3)];
        #pragma unroll
        for (int j = 0; j < 4; ++j)
            bfr[j] = *(const bf16x8*)&Bs[(wn + (j << 4) + l16) * LDAF + (half << 3)];
        #pragma unroll
        for (int i = 0; i < 4; ++i)
            #pragma unroll
            for (int j = 0; j < 4; ++j)
                acc[i][j] = __builtin_amdgcn_mfma_f32_16x16x32_bf16(af[i], bfr[j], acc[i][j], 0, 0, 0);
    }

    #pragma unroll
    for (int i = 0; i < 4; ++i) {
        #pragma unroll
        for (int j = 0; j < 4; ++j) {
            const int ncol = wn + (j << 4) + l16;
            const float a  = act[ncol];
            #pragma unroll
            for (int rg = 0; rg < 4; ++rg) {
                const int m = wm + (i << 4) + (half << 2) + rg;
                out[(((b << 7) + m) << 14) + (h << 7) + ncol] =
                    (acc[i][j][rg] + bias[m]) * a;
            }
        }
    }
}

extern "C" void kernel_launch(void* const* d_in, const int* in_sizes, int n_in,
                              void* d_out, int out_size, void* d_ws, size_t ws_size,
                              hipStream_t stream) {
    const float* x    = (const float*)d_in[0];
    const int*   mask = (const int*)d_in[1];
    const float* wgt  = (const float*)d_in[2];
    const float* bias = (const float*)d_in[3];
    float* out        = (float*)d_out;

    const size_t XP_ELEMS = 4160ull * 4160;   // 17,305,600 bf16 (8*4*130 slabs x 4160)
    const size_t WP_ELEMS = 36ull * 128 * 32; //    147,456 bf16
    const size_t need = (XP_ELEMS + WP_ELEMS) * 2;

    if (ws_size >= need) {
        unsigned short* xpw = (unsigned short*)d_ws;
        unsigned short* wpw = xpw + XP_ELEMS;
        cvt_x3<<<dim3(4160), dim3(256), 0, stream>>>(x, xpw);
        pack_w2<<<dim3(576), dim3(256), 0, stream>>>(wgt, wpw);
        myconv4<<<dim3(512), dim3(256), 0, stream>>>(xpw, mask, wpw, bias, out);
    } else {
        myconv_fb<<<dim3(1024), dim3(256), 0, stream>>>(x, mask, wgt, bias, out);
    }
}

// Round 5
// 150.885 us; speedup vs baseline: 1.4852x; 1.0293x over previous
//
#include <hip/hip_runtime.h>

// MyConv: masked 3x3 conv, B=8, Cin=Cout=128, H=W=128, pad=1, stride=1.
// v5: implicit GEMM over 12 rounds (kh,cb), double-buffered B slab in LDS.
//  - xp[b][cb][hh2=130][w'=130][ci32] bf16, guard rows zero; 16B chunk c of
//    row r stored at slot c ^ ((r + (r>>2)) & 3)  -> conflict-free b128 reads.
//  - Block = 128 threads (2 waves), tile 64 Cout x 2 h-rows x 128 w.
//    Wave tile 64x128, acc 4x8. Grid 1024 -> 4 blocks/CU.
//  - B staged via global_load_lds into Xs[2] (dbuf: stage r+1, compute r,
//    barrier drains overlapped). A fragments direct from global (wp L2-hot).

typedef __bf16 bf16x8 __attribute__((ext_vector_type(8)));
typedef unsigned short u16x8 __attribute__((ext_vector_type(8)));
typedef float f32x4 __attribute__((ext_vector_type(4)));

__device__ __forceinline__ unsigned short f2bf(float f) {
    unsigned int u = __float_as_uint(f);
    u += 0x7fffu + ((u >> 16) & 1u);   // round-to-nearest-even
    return (unsigned short)(u >> 16);
}

// ---- merged setup: cvt x (blocks 0..4159) + pack W (blocks 4160..4735) ----
__global__ void setup_all(const float* __restrict__ x, const float* __restrict__ wgt,
                          unsigned short* __restrict__ xp, unsigned short* __restrict__ wpp) {
    __shared__ float Lf[32 * 132];
    const int t   = threadIdx.x;
    const int bid = blockIdx.x;

    if (bid >= 4160) {   // ---- weight pack: wp[kh][cb][kw][m][ci32] ----
        const int e    = (bid - 4160) * 256 + t;
        const int j    = e & 31;
        const int m    = (e >> 5) & 127;
        const int r    = e >> 12;
        const int kw   = r - (r / 3) * 3;
        const int cbkh = r / 3;
        const int cb   = cbkh & 3;
        const int kh   = cbkh >> 2;
        wpp[e] = f2bf(wgt[((m * 128 + cb * 32 + j) * 3 + kh) * 3 + kw]);
        return;
    }

    // ---- x fp32 [b][ci][h][w] -> bf16 xp slab [(b*4+cb)*130+hh2][r=130][ci32] ----
    const int hh2 = bid % 130;
    const int cb  = (bid / 130) & 3;
    const int b   = bid / 520;
    u16x8* slab = (u16x8*)(xp + (size_t)(((b * 4 + cb) * 130 + hh2)) * 4160);
    const u16x8 z = {0, 0, 0, 0, 0, 0, 0, 0};

    if (hh2 == 0 || hh2 == 129) {      // guard slab
        for (int k = t; k < 520; k += 256) slab[k] = z;
        return;
    }
    const int h = hh2 - 1;

    #pragma unroll
    for (int u = 0; u < 4; ++u) {
        const int f  = t + 256 * u;    // 0..1023
        const int ci = f >> 5;
        const int w4 = f & 31;
        const float4 v = *(const float4*)(x + (((b * 128 + cb * 32 + ci) * 128 + h) << 7) + (w4 << 2));
        *(float4*)&Lf[ci * 132 + (w4 << 2)] = v;
    }
    __syncthreads();

    for (int k = t; k < 520; k += 256) {
        const int r = k >> 2;
        const int c = k & 3;
        u16x8 o;
        if (r == 0 || r == 129) {
            o = z;
        } else {
            const int w   = r - 1;
            const int ci0 = (c ^ ((r + (r >> 2)) & 3)) << 3;   // swizzled ci-group
            #pragma unroll
            for (int s = 0; s < 8; ++s) o[s] = f2bf(Lf[(ci0 + s) * 132 + w]);
        }
        slab[k] = o;
    }
}

__device__ __forceinline__ void stage_slabs(const unsigned char* gx, unsigned char* ls, int t) {
    const int g    = t >> 6;       // wave-uniform
    const int lane = t & 63;
    #pragma unroll
    for (int u = 0; u < 8; ++u)
        __builtin_amdgcn_global_load_lds(
            (const __attribute__((address_space(1))) unsigned int*)(gx + u * 2048 + g * 1024 + lane * 16),
            (__attribute__((address_space(3))) unsigned int*)(ls + u * 2048 + g * 1024),
            16, 0, 0);
    if (t < 16)   // 256B tail, lanes 0-15 of wave 0
        __builtin_amdgcn_global_load_lds(
            (const __attribute__((address_space(1))) unsigned int*)(gx + 16384 + t * 16),
            (__attribute__((address_space(3))) unsigned int*)(ls + 16384),
            16, 0, 0);
}

__global__ __launch_bounds__(128, 2)
void myconv5(const unsigned short* __restrict__ xp,
             const int* __restrict__ mask,
             const unsigned short* __restrict__ wp,
             const float* __restrict__ bias,
             float* __restrict__ out)
{
    __shared__ __align__(16) unsigned char Xs[2][16640];  // dbuf: 2 slabs each
    __shared__ float act[256];

    const int t     = threadIdx.x;       // 0..127
    const int b     = blockIdx.x >> 7;
    const int mhalf = (blockIdx.x >> 6) & 1;
    const int h0    = (blockIdx.x & 63) << 1;

    const int lane = t & 63;
    const int l16  = lane & 15;
    const int q    = lane >> 4;
    const int g    = t >> 6;             // wave -> h row

    const unsigned char* xpB = (const unsigned char*)xp;

    // ---- stage round 0 immediately ----
    stage_slabs(xpB + (size_t)((b * 4 + 0) * 130 + h0 + 0) * 8320, &Xs[0][0], t);

    // ---- active map for rows h0, h0+1 (t = w) ----
    #pragma unroll
    for (int gg = 0; gg < 2; ++gg) {
        const int h = h0 + gg;
        int any = 0;
        #pragma unroll
        for (int kh = 0; kh < 3; ++kh) {
            int hh = h + kh - 1;
            if ((unsigned)hh < 128u) {
                const int* mrow = mask + (b * 128 + hh) * 128;
                #pragma unroll
                for (int kw = 0; kw < 3; ++kw) {
                    int ww = t + kw - 1;
                    if ((unsigned)ww < 128u) any |= mrow[ww];
                }
            }
        }
        act[gg * 128 + t] = any ? 1.0f : 0.0f;
    }

    // B fragment byte offsets (per kw, j-independent swizzle)
    int bb[3];
    #pragma unroll
    for (int kw = 0; kw < 3; ++kw) {
        const int rr   = l16 + kw;
        const int slot = q ^ ((rr + (rr >> 2)) & 3);
        bb[kw] = g * 8320 + rr * 64 + (slot << 4);
    }

    const unsigned char* agl = (const unsigned char*)wp + (mhalf * 64 + l16) * 64 + q * 16;

    f32x4 acc[4][8];
    const f32x4 fzero = {0.f, 0.f, 0.f, 0.f};
    #pragma unroll
    for (int i = 0; i < 4; ++i)
        #pragma unroll
        for (int j = 0; j < 8; ++j)
            acc[i][j] = fzero;

    __syncthreads();   // round-0 staging + act complete

    for (int r = 0; r < 12; ++r) {
        // ---- prefetch round r+1 into the other buffer (no wait here) ----
        if (r < 11) {
            const int rn = r + 1;
            stage_slabs(xpB + (size_t)((b * 4 + (rn & 3)) * 130 + h0 + (rn >> 2)) * 8320,
                        &Xs[(rn & 1)][0], t);
        }

        const unsigned char* ar = agl + r * 24576;
        const unsigned char* xb = &Xs[r & 1][0];
        #pragma unroll
        for (int kw = 0; kw < 3; ++kw) {
            bf16x8 af[4];
            #pragma unroll
            for (int i = 0; i < 4; ++i)
                af[i] = *(const bf16x8*)(ar + kw * 8192 + i * 1024);
            bf16x8 bfr[8];
            #pragma unroll
            for (int j = 0; j < 8; ++j)
                bfr[j] = *(const bf16x8*)(xb + bb[kw] + j * 1024);
            #pragma unroll
            for (int i = 0; i < 4; ++i)
                #pragma unroll
                for (int j = 0; j < 8; ++j)
                    acc[i][j] = __builtin_amdgcn_mfma_f32_16x16x32_bf16(af[i], bfr[j], acc[i][j], 0, 0, 0);
        }

        __syncthreads();   // drains r+1 staging (overlapped with compute above)
    }

    // ---- epilogue: (acc + bias) * active ----
    #pragma unroll
    for (int i = 0; i < 4; ++i) {
        const int m0 = mhalf * 64 + (i << 4) + (q << 2);
        const f32x4 bv = *(const f32x4*)(bias + m0);
        #pragma unroll
        for (int j = 0; j < 8; ++j) {
            const int w = (j << 4) + l16;
            const float a = act[(g << 7) + w];
            float* base = out + (((b << 7) + m0) << 14) + ((h0 + g) << 7) + w;
            #pragma unroll
            for (int rg = 0; rg < 4; ++rg)
                base[rg << 14] = (acc[i][j][rg] + bv[rg]) * a;
        }
    }
}

// ---------------- Round-1 fallback (used only if ws too small) ----------------
#define LDAF 40
__global__ __launch_bounds__(256, 2)
void myconv_fb(const float* __restrict__ x,
               const int* __restrict__ mask,
               const float* __restrict__ wgt,
               const float* __restrict__ bias,
               float* __restrict__ out)
{
    __shared__ unsigned short As[128 * LDAF];
    __shared__ unsigned short Bs[128 * LDAF];
    __shared__ float act[128];

    const int t   = threadIdx.x;
    const int blk = blockIdx.x;
    const int b   = blk >> 7;
    const int h   = blk & 127;

    if (t < 128) {
        int any = 0;
        #pragma unroll
        for (int kh = 0; kh < 3; ++kh) {
            int hh = h + kh - 1;
            if ((unsigned)hh < 128u) {
                const int* mrow = mask + (b * 128 + hh) * 128;
                #pragma unroll
                for (int kw = 0; kw < 3; ++kw) {
                    int ww = t + kw - 1;
                    if ((unsigned)ww < 128u) any |= mrow[ww];
                }
            }
        }
        act[t] = any ? 1.0f : 0.0f;
    }

    const int lane = t & 63;
    const int l16  = lane & 15;
    const int half = lane >> 4;
    const int wv   = t >> 6;
    const int wm   = (wv >> 1) << 6;
    const int wn   = (wv & 1) << 6;

    f32x4 acc[4][4];
    const f32x4 fzero = {0.f, 0.f, 0.f, 0.f};
    #pragma unroll
    for (int i = 0; i < 4; ++i)
        #pragma unroll
        for (int j = 0; j < 4; ++j)
            acc[i][j] = fzero;

    const int am  = t >> 3;
    const int ac4 = (t & 7) << 2;
    const int n     = t & 127;
    const int khalf = __builtin_amdgcn_readfirstlane(t >> 7);
    const int xb    = b << 21;

    for (int kt = 0; kt < 36; ++kt) {
        __syncthreads();
        #pragma unroll
        for (int jj = 0; jj < 4; ++jj) {
            const int m = am + (jj << 5);
            const float4 v = *(const float4*)(wgt + m * 1152 + kt * 32 + ac4);
            unsigned short* dst = &As[m * LDAF + ac4];
            dst[0] = f2bf(v.x); dst[1] = f2bf(v.y); dst[2] = f2bf(v.z); dst[3] = f2bf(v.w);
        }
        u16x8 bv0, bv1;
        #pragma unroll
        for (int s = 0; s < 16; ++s) {
            const int k  = kt * 32 + khalf * 16 + s;
            const int ci = (k * 7282) >> 16;
            const int r  = k - ci * 9;
            const int kh = (r >= 3) + (r >= 6);
            const int kw = r - kh * 3;
            const int hh = h + kh - 1;
            float v = 0.f;
            if ((unsigned)hh < 128u) {
                const int ww = n + kw - 1;
                if ((unsigned)ww < 128u)
                    v = x[xb + (ci << 14) + (hh << 7) + ww];
            }
            if (s < 8) bv0[s] = f2bf(v); else bv1[s - 8] = f2bf(v);
        }
        *(u16x8*)&Bs[n * LDAF + khalf * 16]     = bv0;
        *(u16x8*)&Bs[n * LDAF + khalf * 16 + 8] = bv1;

        __syncthreads();

        bf16x8 af[4], bfr[4];
        #pragma unroll
        for (int i = 0; i < 4; ++i)
            af[i] = *(const bf16x8*)&As[(wm + (i << 4) + l16) * LDAF + (half << 3)];
        #pragma unroll
        for (int j = 0; j < 4; ++j)
            bfr[j] = *(const bf16x8*)&Bs[(wn + (j << 4) + l16) * LDAF + (half << 3)];
        #pragma unroll
        for (int i = 0; i < 4; ++i)
            #pragma unroll
            for (int j = 0; j < 4; ++j)
                acc[i][j] = __builtin_amdgcn_mfma_f32_16x16x32_bf16(af[i], bfr[j], acc[i][j], 0, 0, 0);
    }

    #pragma unroll
    for (int i = 0; i < 4; ++i) {
        #pragma unroll
        for (int j = 0; j < 4; ++j) {
            const int ncol = wn + (j << 4) + l16;
            const float a  = act[ncol];
            #pragma unroll
            for (int rg = 0; rg < 4; ++rg) {
                const int m = wm + (i << 4) + (half << 2) + rg;
                out[(((b << 7) + m) << 14) + (h << 7) + ncol] =
                    (acc[i][j][rg] + bias[m]) * a;
            }
        }
    }
}

extern "C" void kernel_launch(void* const* d_in, const int* in_sizes, int n_in,
                              void* d_out, int out_size, void* d_ws, size_t ws_size,
                              hipStream_t stream) {
    const float* x    = (const float*)d_in[0];
    const int*   mask = (const int*)d_in[1];
    const float* wgt  = (const float*)d_in[2];
    const float* bias = (const float*)d_in[3];
    float* out        = (float*)d_out;

    const size_t XP_ELEMS = 4160ull * 4160;   // 17,305,600 bf16 (8*4*130 slabs)
    const size_t WP_ELEMS = 36ull * 128 * 32; //    147,456 bf16
    const size_t need = (XP_ELEMS + WP_ELEMS) * 2;

    if (ws_size >= need) {
        unsigned short* xpw = (unsigned short*)d_ws;
        unsigned short* wpw = xpw + XP_ELEMS;
        setup_all<<<dim3(4736), dim3(256), 0, stream>>>(x, wgt, xpw, wpw);
        myconv5<<<dim3(1024), dim3(128), 0, stream>>>(xpw, mask, wpw, bias, out);
    } else {
        myconv_fb<<<dim3(1024), dim3(256), 0, stream>>>(x, mask, wgt, bias, out);
    }
}